// Round 6
// baseline (264.426 us; speedup 1.0000x reference)
//
#include <hip/hip_runtime.h>

// CrossAttention: B=4, C=256, H=W=64, N=4096, fp32 in/out.
// ws: Qf16 [B,N,C] @0MB, Kf16 [B,N,C] @8MB, Vt f16 [B,C,N] @16MB, Wf16 [3][O][C] @24MB

typedef __attribute__((ext_vector_type(8))) short short8;
typedef __attribute__((ext_vector_type(4))) float f32x4;
typedef __attribute__((ext_vector_type(4))) int int4v;
typedef __attribute__((ext_vector_type(2))) int int2v;
typedef __attribute__((ext_vector_type(8))) _Float16 half8;
typedef __attribute__((ext_vector_type(4))) _Float16 half4;

#define LOG2E 1.44269504089f

static __device__ __forceinline__ float exp2_fast(float x){ return __builtin_amdgcn_exp2f(x); }

static __device__ __forceinline__ int pk_f16(float a, float b){
  auto h = __builtin_amdgcn_cvt_pkrtz(a, b);   // low=a, high=b
  return __builtin_bit_cast(int, h);
}
static __device__ __forceinline__ unsigned short f2h(float v){
  return __builtin_bit_cast(unsigned short, (_Float16)v);
}

#define GLOAD16(gp, lp) __builtin_amdgcn_global_load_lds( \
  (const __attribute__((address_space(1))) void*)(gp),    \
  (__attribute__((address_space(3))) void*)(lp), 16, 0, 0)

#define MFMA32(a,b,c) __builtin_amdgcn_mfma_f32_16x16x32_f16( \
  __builtin_bit_cast(half8, a), __builtin_bit_cast(half8, b), c, 0, 0, 0)
// NOTE: legacy K=16 intrinsic has no underscore before dtype on gfx950
#define MFMA16(a,b,c) __builtin_amdgcn_mfma_f32_16x16x16f16(a, b, c, 0, 0, 0)

// ---------------------------------------------------------------- W -> f16
__global__ __launch_bounds__(256) void cvt_w(
    const float* __restrict__ wq, const float* __restrict__ wk,
    const float* __restrict__ wv, unsigned short* __restrict__ wf)
{
  const int o = blockIdx.x, t = blockIdx.y, c = threadIdx.x;
  const float* w = (t == 0) ? wq : ((t == 1) ? wk : wv);
  wf[t*65536 + o*256 + c] = f2h(w[o*256 + c]);
}

// ---------------------------------------------------------------- projections (f16 MFMA)
// t=0: Q=Wq*x -> qf [B,N,C]; t=1: K=Wk*y -> kf [B,N,C]; t=2: V=Wv*y -> vtf [B,C,N]
// x-tile [256c][64n] f32 in LDS with per-c-row rotation of 16*((c>>3)&3) elems.
__global__ __launch_bounds__(256, 2) void proj_kernel(
    const float* __restrict__ x, const float* __restrict__ y,
    const unsigned short* __restrict__ wf,
    const float* __restrict__ bq, const float* __restrict__ bk, const float* __restrict__ bv,
    unsigned short* __restrict__ qf, unsigned short* __restrict__ kf,
    unsigned short* __restrict__ vtf)
{
  __shared__ float xs[256*64];   // 64KB

  const int t   = blockIdx.z;
  const int b   = blockIdx.y;
  const int n0  = blockIdx.x * 64;
  const int tid = threadIdx.x;
  const int w   = tid >> 6, lane = tid & 63, g = lane >> 4, l15 = lane & 15;

  const float* src = ((t == 0) ? x : y) + (size_t)b*1048576 + n0;

  // stage 64KB with rotated rows: LDS[c][nn] = x[c][(nn - 16*((c>>3)&3)) & 63]
  #pragma unroll
  for (int i = 0; i < 16; i++){
    int c  = i*16 + (tid >> 4);
    int gg = (c >> 3) & 3;
    int sg = ((tid & 15) - 4*gg) & 15;
    GLOAD16((const char*)src + (size_t)c*16384 + sg*16,
            (char*)xs + (i*256 + tid)*16);
  }
  __syncthreads();

  // x^T fragments: row n_l=l15 (n = n0+w*16+l15), k = cs*32 + g*8 + j
  int4v xf[8];
  {
    const int nn = (w*16 + l15 + 16*g) & 63;   // rotation: (c>>3)&3 == g for all cs,j
    #pragma unroll
    for (int cs = 0; cs < 8; cs++){
      float v[8];
      #pragma unroll
      for (int j = 0; j < 8; j++) v[j] = xs[(cs*32 + g*8 + j)*64 + nn];
      int4v f;
      f[0] = pk_f16(v[0], v[1]); f[1] = pk_f16(v[2], v[3]);
      f[2] = pk_f16(v[4], v[5]); f[3] = pk_f16(v[6], v[7]);
      xf[cs] = f;
    }
  }

  const unsigned short* wt = wf + t*65536;
  const float* bias = (t == 0) ? bq : ((t == 1) ? bk : bv);

  #pragma unroll 4
  for (int ot = 0; ot < 16; ot++){
    f32x4 acc;
    if (t < 2){
      float bo = bias[ot*16 + l15];
      acc = (f32x4){bo, bo, bo, bo};
    } else {
      acc = *(const f32x4*)&bias[ot*16 + g*4];
    }
    #pragma unroll
    for (int cs = 0; cs < 8; cs++){
      short8 wfr = *(const short8*)&wt[(ot*16 + l15)*256 + cs*32 + g*8];
      if (t < 2) acc = MFMA32(__builtin_bit_cast(short8, xf[cs]), wfr, acc);  // D[n][o]
      else       acc = MFMA32(wfr, __builtin_bit_cast(short8, xf[cs]), acc);  // D[o][n]
    }
    if (t < 2){
      unsigned short* outp = (t == 0) ? qf : kf;
      #pragma unroll
      for (int r = 0; r < 4; r++){
        int n = n0 + w*16 + g*4 + r;
        outp[((size_t)(b*4096 + n))*256 + ot*16 + l15] = f2h(acc[r]);
      }
    } else {
      #pragma unroll
      for (int r = 0; r < 4; r++){
        int o = ot*16 + g*4 + r;
        vtf[((size_t)(b*256 + o))*4096 + n0 + w*16 + l15] = f2h(acc[r]);
      }
    }
  }
}

// ---------------------------------------------------------------- attention
// grid (64 n-tiles, 4 b), 512 thr = 4 KV-groups x 2 q-waves x 32 q-rows.
// Group h: KV rows [h*1024,(h+1)*1024), KVBLK=16, double-buffered K/V LDS.
// KVBLK=16 => S-frag (m=g*4+r) feeds K=16 PV MFMA directly (no shuffles).
// 4-group LDS tree-merge (f16 partials), group 0 writes out.
__global__ __launch_bounds__(512, 2) void attn_kernel(
    const unsigned short* __restrict__ qf, const unsigned short* __restrict__ kf,
    const unsigned short* __restrict__ vtf,
    float* __restrict__ out)
{
  __shared__ short k_s[4][2][16*256];   // [grp][buf][m][c], rows 512B, swz ^((m&7)<<4)
  __shared__ short v_s[4][2][256*16];   // [grp][buf][c][m], rows 32B, 16B-granule swz d^(c&1)

  const int tid  = threadIdx.x;
  const int w    = tid >> 6, lane = tid & 63, g = lane >> 4, col = lane & 15;
  const int h    = w >> 1, wq = w & 1;
  const int b    = blockIdx.y;
  const int n0   = blockIdx.x * 64;

  // Q fragments: nn in {0,1}: n = n0 + wq*32 + nn*16 + col, k=c contiguous 8
  short8 qh[2][8];
  #pragma unroll
  for (int nn = 0; nn < 2; nn++){
    size_t qoff = ((size_t)(b*4096 + n0 + wq*32 + nn*16 + col))*256 + g*8;
    #pragma unroll
    for (int ch = 0; ch < 8; ch++)
      qh[nn][ch] = *(const short8*)(qf + qoff + ch*32);
  }

  f32x4 o_acc[2][16];
  #pragma unroll
  for (int nn = 0; nn < 2; nn++)
    #pragma unroll
    for (int i = 0; i < 16; i++){
      o_acc[nn][i][0]=0.f; o_acc[nn][i][1]=0.f; o_acc[nn][i][2]=0.f; o_acc[nn][i][3]=0.f;
    }
  float mst[2] = {-1e30f, -1e30f};
  float lst[2] = {0.f, 0.f};

  // staging source offsets (pre-swizzled so linear gload_lds dest => swizzled LDS)
  int ksrc[4], vsrc[4];
  #pragma unroll
  for (int i = 0; i < 4; i++){
    int s = wq*4 + i;                    // seg in [0,8): 1KB each
    int m = s*2 + (lane >> 5);           // K row (512B rows)
    ksrc[i] = m*512 + (((lane & 31)*16) ^ ((m & 7) << 4));
    int c = s*32 + (lane >> 1);          // V row (32B rows)
    int d = lane & 1;                    // 16B granule
    vsrc[i] = c*8192 + ((d ^ (c & 1)) << 4);
  }

  const char* khg = (const char*)(kf  + ((size_t)b*4096 + h*1024)*256);
  const char* vg  = (const char*)(vtf + ((size_t)b*256)*4096) + h*2048;

  // prologue: stage tile 0 into buf 0
  #pragma unroll
  for (int i = 0; i < 4; i++){
    int s = wq*4 + i;
    GLOAD16(khg + ksrc[i], (char*)&k_s[h][0][0] + s*1024);
    GLOAD16(vg  + vsrc[i], (char*)&v_s[h][0][0] + s*1024);
  }

  int buf = 0;
  for (int it = 0; it < 64; ++it){
    __syncthreads();   // tile `it` staged for all groups

    if (it < 63){      // prefetch next tile AFTER barrier
      const char* kht = khg + (size_t)(it+1)*8192;
      const char* vtt = vg  + (size_t)(it+1)*32;
      #pragma unroll
      for (int i = 0; i < 4; i++){
        int s = wq*4 + i;
        GLOAD16(kht + ksrc[i], (char*)&k_s[h][buf^1][0] + s*1024);
        GLOAD16(vtt + vsrc[i], (char*)&v_s[h][buf^1][0] + s*1024);
      }
    }

    const char* kb = (const char*)&k_s[h][buf][0];
    const char* vb = (const char*)&v_s[h][buf][0];

    // ---- QK^T (swapped): S^T[m][n] = sum_c K[m,c] Q[n,c]; m = 16 rows
    f32x4 s0 = {0.f,0.f,0.f,0.f};
    f32x4 s1 = {0.f,0.f,0.f,0.f};
    __builtin_amdgcn_s_setprio(1);
    #pragma unroll
    for (int ch = 0; ch < 8; ch++){
      int ka = col*512 + ((((ch << 6) | (g << 4))) ^ ((col & 7) << 4));
      short8 kfr = *(const short8*)(kb + ka);
      s0 = MFMA32(kfr, qh[0][ch], s0);
      s1 = MFMA32(kfr, qh[1][ch], s1);
    }
    __builtin_amdgcn_s_setprio(0);

    // ---- online softmax (per nn; lane holds 4 m-values of one n-column)
    float tm0 = fmaxf(fmaxf(s0[0], s0[1]), fmaxf(s0[2], s0[3]));
    tm0 = fmaxf(tm0, __shfl_xor(tm0, 16));
    tm0 = fmaxf(tm0, __shfl_xor(tm0, 32));
    float tm1 = fmaxf(fmaxf(s1[0], s1[1]), fmaxf(s1[2], s1[3]));
    tm1 = fmaxf(tm1, __shfl_xor(tm1, 16));
    tm1 = fmaxf(tm1, __shfl_xor(tm1, 32));

    if (__any(tm0 > mst[0])){
      float mn = fmaxf(mst[0], tm0);
      float sc = exp2_fast((mst[0] - mn) * LOG2E);
      lst[0] *= sc;
      #pragma unroll
      for (int i = 0; i < 16; i++){
        o_acc[0][i][0]*=sc; o_acc[0][i][1]*=sc; o_acc[0][i][2]*=sc; o_acc[0][i][3]*=sc;
      }
      mst[0] = mn;
    }
    if (__any(tm1 > mst[1])){
      float mn = fmaxf(mst[1], tm1);
      float sc = exp2_fast((mst[1] - mn) * LOG2E);
      lst[1] *= sc;
      #pragma unroll
      for (int i = 0; i < 16; i++){
        o_acc[1][i][0]*=sc; o_acc[1][i][1]*=sc; o_acc[1][i][2]*=sc; o_acc[1][i][3]*=sc;
      }
      mst[1] = mn;
    }

    float mb0 = mst[0]*LOG2E, mb1 = mst[1]*LOG2E;
    float p0 = exp2_fast(s0[0]*LOG2E - mb0);
    float p1 = exp2_fast(s0[1]*LOG2E - mb0);
    float p2 = exp2_fast(s0[2]*LOG2E - mb0);
    float p3 = exp2_fast(s0[3]*LOG2E - mb0);
    float p4 = exp2_fast(s1[0]*LOG2E - mb1);
    float p5 = exp2_fast(s1[1]*LOG2E - mb1);
    float p6 = exp2_fast(s1[2]*LOG2E - mb1);
    float p7 = exp2_fast(s1[3]*LOG2E - mb1);

    float ps0 = (p0+p1) + (p2+p3);
    ps0 += __shfl_xor(ps0, 16);
    ps0 += __shfl_xor(ps0, 32);
    lst[0] += ps0;
    float ps1 = (p4+p5) + (p6+p7);
    ps1 += __shfl_xor(ps1, 16);
    ps1 += __shfl_xor(ps1, 32);
    lst[1] += ps1;

    // ---- P fragments: direct (m = g*4+r matches K=16 B-frag k-map), no shuffles
    half4 pf0 = __builtin_bit_cast(half4, (int2v){pk_f16(p0,p1), pk_f16(p2,p3)});
    half4 pf1 = __builtin_bit_cast(half4, (int2v){pk_f16(p4,p5), pk_f16(p6,p7)});

    // ---- PV: O^T[c][n] += sum_m V[m,c] P[n,m]  (K=16 MFMA, vf shared by nn)
    __builtin_amdgcn_s_setprio(1);
    #pragma unroll
    for (int ct = 0; ct < 16; ct++){
      int va = (ct*16 + col)*32 + ((g*8) ^ ((col & 1) << 4));
      half4 vfr = *(const half4*)(vb + va);
      o_acc[0][ct] = MFMA16(vfr, pf0, o_acc[0][ct]);
      o_acc[1][ct] = MFMA16(vfr, pf1, o_acc[1][ct]);
    }
    __builtin_amdgcn_s_setprio(0);

    buf ^= 1;
  }

  // ---- 4-group tree merge via LDS (f16 partials)
  float* mlp = (float*)&k_s[0][0][0];   // (m,l) slots
  int2v* op  = (int2v*)&v_s[0][0][0];   // packed-f16 O slots (2 slots x 2 wq x 2 nn x 16ct x 64 lanes)

  __syncthreads();
  if (h & 1){          // groups 1,3 publish to slot h>>1
    int s = h >> 1;
    #pragma unroll
    for (int nn = 0; nn < 2; nn++){
      #pragma unroll
      for (int ct = 0; ct < 16; ct++){
        f32x4 o = o_acc[nn][ct];
        op[((((s*2 + wq)*2 + nn)*16 + ct)*64) + lane] = (int2v){pk_f16(o[0],o[1]), pk_f16(o[2],o[3])};
      }
      mlp[((((s*2 + wq)*2 + nn)*64) + lane)*2]     = mst[nn];
      mlp[((((s*2 + wq)*2 + nn)*64) + lane)*2 + 1] = lst[nn];
    }
  }
  __syncthreads();
  if (!(h & 1)){       // groups 0,2 merge slot h>>1
    int s = h >> 1;
    #pragma unroll
    for (int nn = 0; nn < 2; nn++){
      float mo = mlp[((((s*2 + wq)*2 + nn)*64) + lane)*2];
      float lo = mlp[((((s*2 + wq)*2 + nn)*64) + lane)*2 + 1];
      float m  = fmaxf(mst[nn], mo);
      float sa = exp2_fast((mst[nn] - m) * LOG2E);
      float sb = exp2_fast((mo      - m) * LOG2E);
      #pragma unroll
      for (int ct = 0; ct < 16; ct++){
        half4 hv = __builtin_bit_cast(half4, op[((((s*2 + wq)*2 + nn)*16 + ct)*64) + lane]);
        f32x4 o = o_acc[nn][ct];
        o[0] = o[0]*sa + (float)hv[0]*sb;
        o[1] = o[1]*sa + (float)hv[1]*sb;
        o[2] = o[2]*sa + (float)hv[2]*sb;
        o[3] = o[3]*sa + (float)hv[3]*sb;
        o_acc[nn][ct] = o;
      }
      mst[nn] = m;
      lst[nn] = lst[nn]*sa + lo*sb;
    }
  }
  __syncthreads();
  if (h == 2){         // publish merged (2,3) to slot 0
    #pragma unroll
    for (int nn = 0; nn < 2; nn++){
      #pragma unroll
      for (int ct = 0; ct < 16; ct++){
        f32x4 o = o_acc[nn][ct];
        op[(((wq*2 + nn)*16 + ct)*64) + lane] = (int2v){pk_f16(o[0],o[1]), pk_f16(o[2],o[3])};
      }
      mlp[(((wq*2 + nn)*64) + lane)*2]     = mst[nn];
      mlp[(((wq*2 + nn)*64) + lane)*2 + 1] = lst[nn];
    }
  }
  __syncthreads();
  if (h == 0){         // final merge + write out[b, c, n]
    #pragma unroll
    for (int nn = 0; nn < 2; nn++){
      float mo = mlp[(((wq*2 + nn)*64) + lane)*2];
      float lo = mlp[(((wq*2 + nn)*64) + lane)*2 + 1];
      float m  = fmaxf(mst[nn], mo);
      float sa = exp2_fast((mst[nn] - m) * LOG2E);
      float sb = exp2_fast((mo      - m) * LOG2E);
      float rl = 1.0f / (lst[nn]*sa + lo*sb);
      sa *= rl; sb *= rl;
      const int outn = n0 + wq*32 + nn*16 + col;
      #pragma unroll
      for (int ct = 0; ct < 16; ct++){
        half4 hv = __builtin_bit_cast(half4, op[(((wq*2 + nn)*16 + ct)*64) + lane]);
        #pragma unroll
        for (int r = 0; r < 4; r++){
          int c = ct*16 + g*4 + r;
          out[((size_t)(b*256 + c))*4096 + outn] = o_acc[nn][ct][r]*sa + (float)hv[r]*sb;
        }
      }
    }
  }
}

// ---------------------------------------------------------------- launch
extern "C" void kernel_launch(void* const* d_in, const int* in_sizes, int n_in,
                              void* d_out, int out_size, void* d_ws, size_t ws_size,
                              hipStream_t stream)
{
  const float* x  = (const float*)d_in[0];
  const float* y  = (const float*)d_in[1];
  const float* Wq = (const float*)d_in[2];
  const float* bq = (const float*)d_in[3];
  const float* Wk = (const float*)d_in[4];
  const float* bk = (const float*)d_in[5];
  const float* Wv = (const float*)d_in[6];
  const float* bv = (const float*)d_in[7];
  float* out = (float*)d_out;

  char* ws = (char*)d_ws;
  const size_t MB = 1048576;
  unsigned short* qf  = (unsigned short*)(ws + 0*MB);
  unsigned short* kfp = (unsigned short*)(ws + 8*MB);
  unsigned short* vtf = (unsigned short*)(ws + 16*MB);
  unsigned short* wf  = (unsigned short*)(ws + 24*MB);

  cvt_w<<<dim3(256,3), dim3(256), 0, stream>>>(Wq, Wk, Wv, wf);
  proj_kernel<<<dim3(64,4,3), dim3(256), 0, stream>>>(x, y, wf, bq, bk, bv,
                                                      qf, kfp, vtf);
  attn_kernel<<<dim3(64,4), dim3(512), 0, stream>>>(qf, kfp, vtf, out);
}